// Round 3
// baseline (562.174 us; speedup 1.0000x reference)
//
#include <hip/hip_runtime.h>
#include <hip/hip_bf16.h>
#include <stdint.h>

typedef __bf16 bf16_t;
typedef bf16_t bf16x8 __attribute__((ext_vector_type(8)));
typedef bf16_t bf16x4 __attribute__((ext_vector_type(4)));
typedef float f32x4 __attribute__((ext_vector_type(4)));

#define NN 10000
#define EE 80000
#define DD 1024
#define LL 2
#define MPAD 10112   /* 79*128 */
#define NEGS 0.2f

#define GLOAD_LDS16(g, l) \
    __builtin_amdgcn_global_load_lds((__attribute__((address_space(1))) void*)(void*)(g), \
                                     (__attribute__((address_space(3))) void*)(l), 16, 0, 0)

// ---------------------------------------------------------------- mega-preamble
__global__ __launch_bounds__(256)
void preamble(const float* __restrict__ Wl, const float* __restrict__ Wr,
              const float* __restrict__ outW, bf16_t* __restrict__ WT,
              bf16_t* __restrict__ OWT,
              const float* __restrict__ x, const int* __restrict__ ntypes,
              const float* __restrict__ nte, bf16_t* __restrict__ hbuf,
              const float* __restrict__ bl, const float* __restrict__ br,
              const float* __restrict__ outb, float* __restrict__ biasb,
              float* __restrict__ M3L, int* __restrict__ deg)
{
    __shared__ float tile[32][33];
    int b = blockIdx.x;
    int tid = threadIdx.x;
    if (b < 5120) {
        int z = b >> 10, rem = b & 1023;
        int bx = rem & 31, by = rem >> 5;
        const float* src;
        bf16_t* dstp;
        switch (z) {
            case 0: src = Wl;                       dstp = WT;                        break;
            case 1: src = Wr;                       dstp = WT + (size_t)1024*1024;    break;
            case 2: src = Wl + (size_t)1024*1024;   dstp = WT + (size_t)2*1024*1024;  break;
            case 3: src = Wr + (size_t)1024*1024;   dstp = WT + (size_t)3*1024*1024;  break;
            default: src = outW;                    dstp = OWT;                       break;
        }
        int tx = tid & 31, ty = tid >> 5;
#pragma unroll
        for (int i = 0; i < 4; ++i)
            tile[ty + i*8][tx] = src[(size_t)(by*32 + ty + i*8)*1024 + bx*32 + tx];
        __syncthreads();
#pragma unroll
        for (int i = 0; i < 4; ++i)
            dstp[(size_t)(bx*32 + ty + i*8)*1024 + by*32 + tx] = (bf16_t)tile[tx][ty + i*8];
    } else if (b < 10176) {
        size_t idx = ((size_t)(b - 5120)*256 + tid) * 8;
        if (idx >= (size_t)MPAD*1024) return;
        int n = (int)(idx >> 10);
        int c = (int)(idx & 1023);
        bf16x8 outv;
        if (n < NN) {
            const float* xp = x + (size_t)n*1024 + c;
            int t = ntypes[n];
            const float* ep = nte + (size_t)t*1024 + c;
#pragma unroll
            for (int j = 0; j < 8; ++j) outv[j] = (bf16_t)(xp[j] + ep[j]);
        } else {
#pragma unroll
            for (int j = 0; j < 8; ++j) outv[j] = (bf16_t)0.f;
        }
        *(bf16x8*)(hbuf + idx) = outv;
    } else if (b < 10196) {
        int i = (b - 10176)*256 + tid;
        if (i < 4096) {
            int l = i >> 11, j = i & 2047;
            biasb[i] = (j < 1024) ? bl[l*1024 + j] : br[l*1024 + j - 1024];
        } else if (i < 5120) {
            biasb[i] = outb[i - 4096];
        }
    } else if (b < 10220) {
        int i = (b - 10196)*256 + tid;
        if (i < LL*3072) M3L[i] = 0.f;
    } else {
        int i = (b - 10220)*256 + tid;
        if (i < NN) deg[i] = 0;
    }
}

// ---------------------------------------------------------------- M3 (both layers, one launch)
__global__ __launch_bounds__(256)
void compute_m3_all(const float* __restrict__ ete, const float* __restrict__ We,
                    float* __restrict__ M3L)
{
    int l   = blockIdx.x >> 8;
    int bid = blockIdx.x & 255;
    const float* WeL = We + (size_t)l*1024*1024;
    float* M3 = M3L + l*3072;
    int j  = (bid & 3) * 256 + threadIdx.x;
    int k0 = (bid >> 2) * 16;
    float a0 = 0.f, a1 = 0.f, a2 = 0.f;
#pragma unroll
    for (int kk = 0; kk < 16; ++kk) {
        int k = k0 + kk;
        float w = WeL[(size_t)k*1024 + j];
        a0 += ete[k]        * w;
        a1 += ete[1024 + k] * w;
        a2 += ete[2048 + k] * w;
    }
    atomicAdd(&M3[j],        a0);
    atomicAdd(&M3[1024 + j], a1);
    atomicAdd(&M3[2048 + j], a2);
}

// ---------------------------------------------------------------- CSR build
__global__ void hist_k(const int* __restrict__ dsts, int* __restrict__ deg)
{ int e = blockIdx.x*256 + threadIdx.x; if (e < EE) atomicAdd(&deg[dsts[e]], 1); }

__global__ __launch_bounds__(1024)
void scan_csr(const int* __restrict__ deg, int* __restrict__ rp, int* __restrict__ cursor)
{
    __shared__ int tot[1024];
    int t = threadIdx.x;
    int base = t * 10;
    int v[10];
    int run = 0;
#pragma unroll
    for (int j = 0; j < 10; ++j) {
        int i = base + j;
        int d = (i < NN) ? deg[i] : 0;
        run += d;
        v[j] = run;
    }
    tot[t] = run;
    __syncthreads();
    for (int d = 1; d < 1024; d <<= 1) {
        int xv = (t >= d) ? tot[t - d] : 0;
        __syncthreads();
        tot[t] += xv;
        __syncthreads();
    }
    int ex = (t == 0) ? 0 : tot[t - 1];
#pragma unroll
    for (int j = 0; j < 10; ++j) {
        int i = base + j;
        if (i < NN) {
            int incl = ex + v[j];
            rp[i + 1] = incl;
            if (i + 1 < NN) cursor[i + 1] = incl;
        }
    }
    if (t == 0) { rp[0] = 0; cursor[0] = 0; }
}

__global__ void fill_csr(const int* __restrict__ srcs, const int* __restrict__ dsts,
                         const int* __restrict__ etype, int* __restrict__ cursor,
                         int* __restrict__ sorted_src, int* __restrict__ sorted_typ)
{
    int e = blockIdx.x*256 + threadIdx.x;
    if (e < EE) {
        int d = dsts[e];
        int pos = atomicAdd(&cursor[d], 1);
        sorted_src[pos] = srcs[e];
        sorted_typ[pos] = etype[e];
    }
}

// ---------------------------------------------------------------- GEMM: BK=64 + XOR-swizzled LDS
// (proven m97-structure: 32 KiB LDS, 80 VGPR -> 5 blocks/CU, whole grid co-resident)
template <typename OT>
__global__ __launch_bounds__(256)
void gemm_bt(const bf16_t* __restrict__ A, const bf16_t* __restrict__ BT,
             const float* __restrict__ bias, OT* __restrict__ Cmat,
             int K, int Ntot, int storeM, int mtiles, int ntiles)
{
    __shared__ __align__(16) bf16_t As[128*64];
    __shared__ __align__(16) bf16_t Bs[128*64];
    const int tid  = threadIdx.x;
    const int wave = tid >> 6;
    const int lane = tid & 63;

    const int GROUP_M = 8;
    int pid = blockIdx.x;
    int in_group = GROUP_M * ntiles;
    int gid = pid / in_group;
    int first_m = gid * GROUP_M;
    int gsz = mtiles - first_m; if (gsz > GROUP_M) gsz = GROUP_M;
    int local = pid % in_group;
    const int m0 = (first_m + (local % gsz)) * 128;
    const int n0 = (local / gsz) * 128;

    const int wm = (wave & 1) * 64;
    const int wn = (wave >> 1) * 64;
    const int quad = lane >> 4;
    const int l16  = lane & 15;

    const int srow = lane >> 3;
    const int gcol = ((lane & 7) ^ srow) * 8;

    f32x4 acc[4][4];
    f32x4 zero = {0.f, 0.f, 0.f, 0.f};
#pragma unroll
    for (int i = 0; i < 4; ++i)
#pragma unroll
        for (int j = 0; j < 4; ++j) acc[i][j] = zero;

    const bf16_t* aBase = A  + (size_t)(m0 + wave*8 + srow) * K + gcol;
    const bf16_t* bBase = BT + (size_t)(n0 + wave*8 + srow) * K + gcol;
    bf16_t* asDst = As + wave*512;
    bf16_t* bsDst = Bs + wave*512;

    for (int k0 = 0; k0 < K; k0 += 64) {
#pragma unroll
        for (int j = 0; j < 4; ++j)
            GLOAD_LDS16(aBase + (size_t)(j*32)*K + k0, asDst + j*2048);
#pragma unroll
        for (int j = 0; j < 4; ++j)
            GLOAD_LDS16(bBase + (size_t)(j*32)*K + k0, bsDst + j*2048);
        __syncthreads();
#pragma unroll
        for (int kk = 0; kk < 2; ++kk) {
            bf16x8 af[4], bfr[4];
#pragma unroll
            for (int mi = 0; mi < 4; ++mi) {
                int row = wm + mi*16 + l16;
                int ch  = ((kk*4 + quad) ^ (row & 7)) * 8;
                af[mi] = *(const bf16x8*)(As + row*64 + ch);
            }
#pragma unroll
            for (int ni = 0; ni < 4; ++ni) {
                int row = wn + ni*16 + l16;
                int ch  = ((kk*4 + quad) ^ (row & 7)) * 8;
                bfr[ni] = *(const bf16x8*)(Bs + row*64 + ch);
            }
#pragma unroll
            for (int mi = 0; mi < 4; ++mi)
#pragma unroll
                for (int ni = 0; ni < 4; ++ni)
                    acc[mi][ni] = __builtin_amdgcn_mfma_f32_16x16x32_bf16(af[mi], bfr[ni], acc[mi][ni], 0, 0, 0);
        }
        __syncthreads();
    }

#pragma unroll
    for (int mi = 0; mi < 4; ++mi) {
#pragma unroll
        for (int ni = 0; ni < 4; ++ni) {
            int col = n0 + wn + ni*16 + l16;
            float bv = bias[col];
#pragma unroll
            for (int r = 0; r < 4; ++r) {
                int row = m0 + wm + mi*16 + quad*4 + r;
                if (row < storeM)
                    Cmat[(size_t)row * Ntot + col] = (OT)(acc[mi][ni][r] + bv);
            }
        }
    }
}

// ---------------------------------------------------------------- fused: logits + softmax + aggregate + residual
// v2: 8 ch/thread, 2 edges in flight (halves), bf16x8 loads, 4-shfl head reduce
__global__ __launch_bounds__(256)
void fused_edge(const int* __restrict__ rp, const int* __restrict__ ssrc,
                const int* __restrict__ styp, const bf16_t* __restrict__ XLXR,
                const float* __restrict__ M3, const float* __restrict__ attv,
                const float* __restrict__ cbias, bf16_t* __restrict__ hbuf)
{
    int node = blockIdx.x;
    int tid = threadIdx.x;
    int eh = tid >> 7;          // edge half: 0 = even edges, 1 = odd edges
    int q  = tid & 127;         // channel group (8 ch each)
    int c8 = q * 8;

    __shared__ int s_src[256];
    __shared__ int s_typ[256];
    __shared__ float red[12][128];   // a0..7, den, cnt0..2 from half 1

    int b = rp[node], en = rp[node + 1];

    bf16x8 xrv8 = *(const bf16x8*)(XLXR + (size_t)node*2048 + 1024 + c8);
    float xr[8];
#pragma unroll
    for (int j = 0; j < 8; ++j) xr[j] = (float)xrv8[j];
    f32x4 atl = *(const f32x4*)(attv + c8);
    f32x4 ath = *(const f32x4*)(attv + c8 + 4);
    float at[8] = {atl[0], atl[1], atl[2], atl[3], ath[0], ath[1], ath[2], ath[3]};
    float m3r[3][8];
#pragma unroll
    for (int t = 0; t < 3; ++t) {
        f32x4 ml = *(const f32x4*)(M3 + t*1024 + c8);
        f32x4 mh = *(const f32x4*)(M3 + t*1024 + c8 + 4);
#pragma unroll
        for (int j = 0; j < 4; ++j) { m3r[t][j] = ml[j]; m3r[t][4+j] = mh[j]; }
    }

    float acc[8] = {0.f, 0.f, 0.f, 0.f, 0.f, 0.f, 0.f, 0.f};
    float den = 0.f;
    float cnt0 = 0.f, cnt1 = 0.f, cnt2 = 0.f;

    for (int base = b; base < en; base += 256) {
        int nchunk = en - base; if (nchunk > 256) nchunk = 256;
        __syncthreads();
        if (tid < nchunk) { s_src[tid] = ssrc[base + tid]; s_typ[tid] = styp[base + tid]; }
        __syncthreads();
#pragma unroll 2
        for (int i = eh; i < nchunk; i += 2) {
            int s = s_src[i];
            int t = s_typ[i];
            bf16x8 xs = *(const bf16x8*)(XLXR + (size_t)s*2048 + c8);
            float x[8];
            float part = 0.f;
#pragma unroll
            for (int j = 0; j < 8; ++j) {
                x[j] = (float)xs[j];
                float v = x[j] + xr[j] + m3r[t][j];
                v = (v > 0.f) ? v : NEGS * v;
                part += v * at[j];
            }
            part += __shfl_xor(part, 1);
            part += __shfl_xor(part, 2);
            part += __shfl_xor(part, 4);
            part += __shfl_xor(part, 8);
            part = fminf(fmaxf(part, -60.f), 60.f);
            float p = __expf(part);
            cnt0 += (t == 0) ? 1.f : 0.f;
            cnt1 += (t == 1) ? 1.f : 0.f;
            cnt2 += (t == 2) ? 1.f : 0.f;
            den += p;
#pragma unroll
            for (int j = 0; j < 8; ++j) acc[j] += p * x[j];
        }
    }

    // combine the two edge-halves
    __syncthreads();
    if (eh == 1) {
#pragma unroll
        for (int j = 0; j < 8; ++j) red[j][q] = acc[j];
        red[8][q] = den; red[9][q] = cnt0; red[10][q] = cnt1; red[11][q] = cnt2;
    }
    __syncthreads();
    if (eh == 0) {
#pragma unroll
        for (int j = 0; j < 8; ++j) acc[j] += red[j][q];
        den  += red[8][q];
        cnt0 += red[9][q]; cnt1 += red[10][q]; cnt2 += red[11][q];

        float degf = cnt0 + cnt1 + cnt2;
        float inv = 1.f / fmaxf(degf, 1.f);
        float w0 = cnt0 * inv, w1 = cnt1 * inv, w2 = cnt2 * inv;

        bf16x8 xlv8 = *(const bf16x8*)(XLXR + (size_t)node*2048 + c8);
        float sx[8];
        float sp = 0.f;
#pragma unroll
        for (int j = 0; j < 8; ++j) {
            sx[j] = (float)xlv8[j];
            float e = w0*m3r[0][j] + w1*m3r[1][j] + w2*m3r[2][j];
            float u = sx[j] + xr[j] + e;
            u = (u > 0.f) ? u : NEGS * u;
            sp += u * at[j];
        }
        sp += __shfl_xor(sp, 1);
        sp += __shfl_xor(sp, 2);
        sp += __shfl_xor(sp, 4);
        sp += __shfl_xor(sp, 8);
        sp = fminf(fmaxf(sp, -60.f), 60.f);
        float ps = __expf(sp);
        den += ps;
#pragma unroll
        for (int j = 0; j < 8; ++j) acc[j] += ps * sx[j];

        float invd = 1.f / den;
        bf16x8 hv = *(const bf16x8*)(hbuf + (size_t)node*1024 + c8);
        bf16x8 outv;
#pragma unroll
        for (int j = 0; j < 8; ++j)
            outv[j] = (bf16_t)((float)hv[j] + fmaxf(acc[j]*invd + cbias[c8 + j], 0.f));
        *(bf16x8*)(hbuf + (size_t)node*1024 + c8) = outv;
    }
}

// ---------------------------------------------------------------- launch
extern "C" void kernel_launch(void* const* d_in, const int* in_sizes, int n_in,
                              void* d_out, int out_size, void* d_ws, size_t ws_size,
                              hipStream_t stream)
{
    (void)in_sizes; (void)n_in; (void)out_size; (void)ws_size;
    const float* x     = (const float*)d_in[0];
    const int*   eidx  = (const int*)d_in[1];
    const int*   etype = (const int*)d_in[2];
    const int*   ntyp  = (const int*)d_in[3];
    const float* nte   = (const float*)d_in[4];
    const float* ete   = (const float*)d_in[5];
    const float* Wl    = (const float*)d_in[6];
    const float* bl    = (const float*)d_in[7];
    const float* Wr    = (const float*)d_in[8];
    const float* br    = (const float*)d_in[9];
    const float* We    = (const float*)d_in[10];
    const float* attw  = (const float*)d_in[11];
    const float* cbias = (const float*)d_in[12];
    const float* outW  = (const float*)d_in[13];
    const float* outb  = (const float*)d_in[14];
    const int* srcs = eidx;
    const int* dsts = eidx + EE;

    char* wsp = (char*)d_ws;
    size_t off = 0;
    auto carve = [&](size_t bytes) -> void* {
        void* pp = wsp + off;
        off += (bytes + 255) & ~(size_t)255;
        return pp;
    };
    bf16_t* hbuf  = (bf16_t*)carve((size_t)MPAD*1024*2);
    bf16_t* XLXR  = (bf16_t*)carve((size_t)MPAD*2048*2);
    bf16_t* WT    = (bf16_t*)carve((size_t)LL*2048*1024*2);
    bf16_t* OWT   = (bf16_t*)carve((size_t)1024*1024*2);
    float*  M3L   = (float*)carve((size_t)LL*3072*4);
    float*  biasb = (float*)carve(5120*4);
    int* deg    = (int*)carve((size_t)NN*4);
    int* rp     = (int*)carve((size_t)(NN+1)*4);
    int* cursor = (int*)carve((size_t)NN*4);
    int* ssrc   = (int*)carve((size_t)EE*4);
    int* styp   = (int*)carve((size_t)EE*4);

    preamble<<<10260, 256, 0, stream>>>(Wl, Wr, outW, WT, OWT,
                                        x, ntyp, nte, hbuf,
                                        bl, br, outb, biasb, M3L, deg);
    compute_m3_all<<<512, 256, 0, stream>>>(ete, We, M3L);
    hist_k<<<(EE + 255)/256, 256, 0, stream>>>(dsts, deg);
    scan_csr<<<1, 1024, 0, stream>>>(deg, rp, cursor);
    fill_csr<<<(EE + 255)/256, 256, 0, stream>>>(srcs, dsts, etype, cursor, ssrc, styp);

    for (int l = 0; l < LL; ++l) {
        gemm_bt<bf16_t><<<79*16, 256, 0, stream>>>(hbuf, WT + (size_t)l*2048*1024,
                                                   biasb + l*2048, XLXR,
                                                   1024, 2048, MPAD, 79, 16);
        fused_edge<<<NN, 256, 0, stream>>>(rp, ssrc, styp, XLXR, M3L + l*3072, attw + l*1024,
                                           cbias + l*1024, hbuf);
    }

    gemm_bt<float><<<79*8, 256, 0, stream>>>(hbuf, OWT, biasb + 4096, (float*)d_out,
                                             1024, 1024, NN, 79, 8);
}

// Round 4
// 427.579 us; speedup vs baseline: 1.3148x; 1.3148x over previous
//
#include <hip/hip_runtime.h>
#include <hip/hip_bf16.h>
#include <stdint.h>

typedef __bf16 bf16_t;
typedef bf16_t bf16x8 __attribute__((ext_vector_type(8)));
typedef bf16_t bf16x4 __attribute__((ext_vector_type(4)));
typedef float f32x4 __attribute__((ext_vector_type(4)));

#define NN 10000
#define EE 80000
#define DD 1024
#define LL 2
#define MPAD 10112   /* 79*128 */
#define NEGS 0.2f

#define GLOAD_LDS16(g, l) \
    __builtin_amdgcn_global_load_lds((__attribute__((address_space(1))) void*)(void*)(g), \
                                     (__attribute__((address_space(3))) void*)(l), 16, 0, 0)

// ---------------------------------------------------------------- mega-preamble
__global__ __launch_bounds__(256)
void preamble(const float* __restrict__ Wl, const float* __restrict__ Wr,
              const float* __restrict__ outW, bf16_t* __restrict__ WT,
              bf16_t* __restrict__ OWT,
              const float* __restrict__ x, const int* __restrict__ ntypes,
              const float* __restrict__ nte, bf16_t* __restrict__ hbuf,
              const float* __restrict__ bl, const float* __restrict__ br,
              const float* __restrict__ outb, float* __restrict__ biasb,
              float* __restrict__ M3L, int* __restrict__ deg3)
{
    __shared__ float tile[32][33];
    int b = blockIdx.x;
    int tid = threadIdx.x;
    if (b < 5120) {
        int z = b >> 10, rem = b & 1023;
        int bx = rem & 31, by = rem >> 5;
        const float* src;
        bf16_t* dstp;
        switch (z) {
            case 0: src = Wl;                       dstp = WT;                        break;
            case 1: src = Wr;                       dstp = WT + (size_t)1024*1024;    break;
            case 2: src = Wl + (size_t)1024*1024;   dstp = WT + (size_t)2*1024*1024;  break;
            case 3: src = Wr + (size_t)1024*1024;   dstp = WT + (size_t)3*1024*1024;  break;
            default: src = outW;                    dstp = OWT;                       break;
        }
        int tx = tid & 31, ty = tid >> 5;
#pragma unroll
        for (int i = 0; i < 4; ++i)
            tile[ty + i*8][tx] = src[(size_t)(by*32 + ty + i*8)*1024 + bx*32 + tx];
        __syncthreads();
#pragma unroll
        for (int i = 0; i < 4; ++i)
            dstp[(size_t)(bx*32 + ty + i*8)*1024 + by*32 + tx] = (bf16_t)tile[tx][ty + i*8];
    } else if (b < 10176) {
        size_t idx = ((size_t)(b - 5120)*256 + tid) * 8;
        if (idx >= (size_t)MPAD*1024) return;
        int n = (int)(idx >> 10);
        int c = (int)(idx & 1023);
        bf16x8 outv;
        if (n < NN) {
            const float* xp = x + (size_t)n*1024 + c;
            int t = ntypes[n];
            const float* ep = nte + (size_t)t*1024 + c;
#pragma unroll
            for (int j = 0; j < 8; ++j) outv[j] = (bf16_t)(xp[j] + ep[j]);
        } else {
#pragma unroll
            for (int j = 0; j < 8; ++j) outv[j] = (bf16_t)0.f;
        }
        *(bf16x8*)(hbuf + idx) = outv;
    } else if (b < 10196) {
        int i = (b - 10176)*256 + tid;
        if (i < 4096) {
            int l = i >> 11, j = i & 2047;
            biasb[i] = (j < 1024) ? bl[l*1024 + j] : br[l*1024 + j - 1024];
        } else if (i < 5120) {
            biasb[i] = outb[i - 4096];
        }
    } else if (b < 10220) {
        int i = (b - 10196)*256 + tid;
        if (i < LL*3072) M3L[i] = 0.f;
    } else {
        int i = (b - 10220)*256 + tid;
        if (i < 3*NN) deg3[i] = 0;
    }
}

// ---------------------------------------------------------------- M3 (both layers, one launch)
__global__ __launch_bounds__(256)
void compute_m3_all(const float* __restrict__ ete, const float* __restrict__ We,
                    float* __restrict__ M3L)
{
    int l   = blockIdx.x >> 8;
    int bid = blockIdx.x & 255;
    const float* WeL = We + (size_t)l*1024*1024;
    float* M3 = M3L + l*3072;
    int j  = (bid & 3) * 256 + threadIdx.x;
    int k0 = (bid >> 2) * 16;
    float a0 = 0.f, a1 = 0.f, a2 = 0.f;
#pragma unroll
    for (int kk = 0; kk < 16; ++kk) {
        int k = k0 + kk;
        float w = WeL[(size_t)k*1024 + j];
        a0 += ete[k]        * w;
        a1 += ete[1024 + k] * w;
        a2 += ete[2048 + k] * w;
    }
    atomicAdd(&M3[j],        a0);
    atomicAdd(&M3[1024 + j], a1);
    atomicAdd(&M3[2048 + j], a2);
}

// ---------------------------------------------------------------- CSR build (type-segmented)
__global__ void hist_k(const int* __restrict__ dsts, const int* __restrict__ etype,
                       int* __restrict__ deg3)
{
    int e = blockIdx.x*256 + threadIdx.x;
    if (e < EE) atomicAdd(&deg3[dsts[e]*3 + etype[e]], 1);
}

__global__ __launch_bounds__(1024)
void scan_csr(const int* __restrict__ deg3, int* __restrict__ rp3, int* __restrict__ cursor3)
{
    __shared__ int tot[1024];
    int t = threadIdx.x;
    int base = t * 30;
    int v[30];
    int run = 0;
#pragma unroll
    for (int j = 0; j < 30; ++j) {
        int i = base + j;
        int d = (i < 3*NN) ? deg3[i] : 0;
        run += d;
        v[j] = run;
    }
    tot[t] = run;
    __syncthreads();
    for (int d = 1; d < 1024; d <<= 1) {
        int xv = (t >= d) ? tot[t - d] : 0;
        __syncthreads();
        tot[t] += xv;
        __syncthreads();
    }
    int ex = (t == 0) ? 0 : tot[t - 1];
#pragma unroll
    for (int j = 0; j < 30; ++j) {
        int i = base + j;
        if (i < 3*NN) {
            int incl = ex + v[j];
            rp3[i + 1] = incl;
            if (i + 1 < 3*NN) cursor3[i + 1] = incl;
        }
    }
    if (t == 0) { rp3[0] = 0; cursor3[0] = 0; }
}

__global__ void fill_csr(const int* __restrict__ srcs, const int* __restrict__ dsts,
                         const int* __restrict__ etype, int* __restrict__ cursor3,
                         int* __restrict__ sorted_src)
{
    int e = blockIdx.x*256 + threadIdx.x;
    if (e < EE) {
        int d = dsts[e];
        int t = etype[e];
        int pos = atomicAdd(&cursor3[d*3 + t], 1);
        sorted_src[pos] = srcs[e];
    }
}

// ---------------------------------------------------------------- GEMM: BK=64 + XOR-swizzled LDS
// (proven m97-structure: 32 KiB LDS, 80 VGPR -> 5 blocks/CU, whole grid co-resident)
template <typename OT>
__global__ __launch_bounds__(256)
void gemm_bt(const bf16_t* __restrict__ A, const bf16_t* __restrict__ BT,
             const float* __restrict__ bias, OT* __restrict__ Cmat,
             int K, int Ntot, int storeM, int mtiles, int ntiles)
{
    __shared__ __align__(16) bf16_t As[128*64];
    __shared__ __align__(16) bf16_t Bs[128*64];
    const int tid  = threadIdx.x;
    const int wave = tid >> 6;
    const int lane = tid & 63;

    const int GROUP_M = 8;
    int pid = blockIdx.x;
    int in_group = GROUP_M * ntiles;
    int gid = pid / in_group;
    int first_m = gid * GROUP_M;
    int gsz = mtiles - first_m; if (gsz > GROUP_M) gsz = GROUP_M;
    int local = pid % in_group;
    const int m0 = (first_m + (local % gsz)) * 128;
    const int n0 = (local / gsz) * 128;

    const int wm = (wave & 1) * 64;
    const int wn = (wave >> 1) * 64;
    const int quad = lane >> 4;
    const int l16  = lane & 15;

    const int srow = lane >> 3;
    const int gcol = ((lane & 7) ^ srow) * 8;

    f32x4 acc[4][4];
    f32x4 zero = {0.f, 0.f, 0.f, 0.f};
#pragma unroll
    for (int i = 0; i < 4; ++i)
#pragma unroll
        for (int j = 0; j < 4; ++j) acc[i][j] = zero;

    const bf16_t* aBase = A  + (size_t)(m0 + wave*8 + srow) * K + gcol;
    const bf16_t* bBase = BT + (size_t)(n0 + wave*8 + srow) * K + gcol;
    bf16_t* asDst = As + wave*512;
    bf16_t* bsDst = Bs + wave*512;

    for (int k0 = 0; k0 < K; k0 += 64) {
#pragma unroll
        for (int j = 0; j < 4; ++j)
            GLOAD_LDS16(aBase + (size_t)(j*32)*K + k0, asDst + j*2048);
#pragma unroll
        for (int j = 0; j < 4; ++j)
            GLOAD_LDS16(bBase + (size_t)(j*32)*K + k0, bsDst + j*2048);
        __syncthreads();
#pragma unroll
        for (int kk = 0; kk < 2; ++kk) {
            bf16x8 af[4], bfr[4];
#pragma unroll
            for (int mi = 0; mi < 4; ++mi) {
                int row = wm + mi*16 + l16;
                int ch  = ((kk*4 + quad) ^ (row & 7)) * 8;
                af[mi] = *(const bf16x8*)(As + row*64 + ch);
            }
#pragma unroll
            for (int ni = 0; ni < 4; ++ni) {
                int row = wn + ni*16 + l16;
                int ch  = ((kk*4 + quad) ^ (row & 7)) * 8;
                bfr[ni] = *(const bf16x8*)(Bs + row*64 + ch);
            }
#pragma unroll
            for (int mi = 0; mi < 4; ++mi)
#pragma unroll
                for (int ni = 0; ni < 4; ++ni)
                    acc[mi][ni] = __builtin_amdgcn_mfma_f32_16x16x32_bf16(af[mi], bfr[ni], acc[mi][ni], 0, 0, 0);
        }
        __syncthreads();
    }

#pragma unroll
    for (int mi = 0; mi < 4; ++mi) {
#pragma unroll
        for (int ni = 0; ni < 4; ++ni) {
            int col = n0 + wn + ni*16 + l16;
            float bv = bias[col];
#pragma unroll
            for (int r = 0; r < 4; ++r) {
                int row = m0 + wm + mi*16 + quad*4 + r;
                if (row < storeM)
                    Cmat[(size_t)row * Ntot + col] = (OT)(acc[mi][ni][r] + bv);
            }
        }
    }
}

// ---------------------------------------------------------------- fused: logits + softmax + aggregate + residual
// v3: type-segmented CSR -> all m3/type handling is compile-time static; per-edge body
// has no selects, no s_typ, no cnt ops.
__global__ __launch_bounds__(256)
void fused_edge(const int* __restrict__ rp3, const int* __restrict__ ssrc,
                const bf16_t* __restrict__ XLXR,
                const float* __restrict__ M3, const float* __restrict__ attv,
                const float* __restrict__ cbias, bf16_t* __restrict__ hbuf)
{
    int node = blockIdx.x;
    int tid = threadIdx.x;
    int c = tid * 4;
    __shared__ int s_src[256];

    int b   = rp3[3*node];
    int t1g = rp3[3*node + 1];
    int t2g = rp3[3*node + 2];
    int en  = rp3[3*node + 3];

    bf16x4 xlv = *(const bf16x4*)(XLXR + (size_t)node*2048 + c);
    bf16x4 xrv = *(const bf16x4*)(XLXR + (size_t)node*2048 + 1024 + c);
    float xr0 = (float)xrv[0], xr1 = (float)xrv[1], xr2 = (float)xrv[2], xr3 = (float)xrv[3];
    float at0 = attv[c], at1 = attv[c+1], at2 = attv[c+2], at3 = attv[c+3];

    // premerged per-type rows (xr + m3[t]) -- STATIC register indexing everywhere
    float q00 = xr0 + M3[c+0],      q01 = xr1 + M3[c+1],      q02 = xr2 + M3[c+2],      q03 = xr3 + M3[c+3];
    float q10 = xr0 + M3[1024+c+0], q11 = xr1 + M3[1024+c+1], q12 = xr2 + M3[1024+c+2], q13 = xr3 + M3[1024+c+3];
    float q20 = xr0 + M3[2048+c+0], q21 = xr1 + M3[2048+c+1], q22 = xr2 + M3[2048+c+2], q23 = xr3 + M3[2048+c+3];

    float a0 = 0.f, a1 = 0.f, a2 = 0.f, a3 = 0.f;
    float den = 0.f;

    auto body = [&](int li, float p0, float p1, float p2, float p3) {
        int s = s_src[li];
        bf16x4 xs = *(const bf16x4*)(XLXR + (size_t)s*2048 + c);
        float x0 = (float)xs[0], x1 = (float)xs[1], x2 = (float)xs[2], x3 = (float)xs[3];
        float v0 = x0 + p0; v0 = (v0 > 0.f) ? v0 : NEGS * v0;
        float v1 = x1 + p1; v1 = (v1 > 0.f) ? v1 : NEGS * v1;
        float v2 = x2 + p2; v2 = (v2 > 0.f) ? v2 : NEGS * v2;
        float v3 = x3 + p3; v3 = (v3 > 0.f) ? v3 : NEGS * v3;
        float part = v0*at0 + v1*at1 + v2*at2 + v3*at3;
        part += __shfl_xor(part, 1);
        part += __shfl_xor(part, 2);
        part += __shfl_xor(part, 4);
        part += __shfl_xor(part, 8);
        part += __shfl_xor(part, 16);
        part = fminf(fmaxf(part, -60.f), 60.f);
        float p = __expf(part);
        den += p;
        a0 += p * x0; a1 += p * x1; a2 += p * x2; a3 += p * x3;
    };

    for (int base = b; base < en; base += 256) {
        int hi = en - base; if (hi > 256) hi = 256;
        hi += base;                       // global end of this chunk
        __syncthreads();
        if (tid < hi - base) s_src[tid] = ssrc[base + tid];
        __syncthreads();
        int e0 = (t1g < hi) ? t1g : hi;   // type-0 end within chunk
        int e1 = (t2g < hi) ? t2g : hi;   // type-1 end within chunk
        int s1 = (t1g > base) ? t1g : base;
        int s2 = (t2g > base) ? t2g : base;
#pragma unroll 2
        for (int i = base; i < e0; ++i) body(i - base, q00, q01, q02, q03);
#pragma unroll 2
        for (int i = s1; i < e1; ++i)   body(i - base, q10, q11, q12, q13);
#pragma unroll 2
        for (int i = s2; i < hi; ++i)   body(i - base, q20, q21, q22, q23);
    }

    float cnt0 = (float)(t1g - b);
    float cnt1 = (float)(t2g - t1g);
    float cnt2 = (float)(en - t2g);
    float degf = cnt0 + cnt1 + cnt2;
    float inv = 1.f / fmaxf(degf, 1.f);
    float w0 = cnt0 * inv, w1 = cnt1 * inv, w2 = cnt2 * inv;
    float sw = w0 + w1 + w2;              // 1 if deg>0 else 0
    float sx0 = (float)xlv[0], sx1 = (float)xlv[1], sx2 = (float)xlv[2], sx3 = (float)xlv[3];
    float u0 = sx0 + xr0*(1.f - sw) + w0*q00 + w1*q10 + w2*q20; u0 = (u0 > 0.f) ? u0 : NEGS * u0;
    float u1 = sx1 + xr1*(1.f - sw) + w0*q01 + w1*q11 + w2*q21; u1 = (u1 > 0.f) ? u1 : NEGS * u1;
    float u2 = sx2 + xr2*(1.f - sw) + w0*q02 + w1*q12 + w2*q22; u2 = (u2 > 0.f) ? u2 : NEGS * u2;
    float u3 = sx3 + xr3*(1.f - sw) + w0*q03 + w1*q13 + w2*q23; u3 = (u3 > 0.f) ? u3 : NEGS * u3;
    float sp = u0*at0 + u1*at1 + u2*at2 + u3*at3;
    sp += __shfl_xor(sp, 1);
    sp += __shfl_xor(sp, 2);
    sp += __shfl_xor(sp, 4);
    sp += __shfl_xor(sp, 8);
    sp += __shfl_xor(sp, 16);
    sp = fminf(fmaxf(sp, -60.f), 60.f);
    float ps = __expf(sp);
    den += ps;
    a0 += ps * sx0; a1 += ps * sx1; a2 += ps * sx2; a3 += ps * sx3;

    float invd = 1.f / den;
    bf16x4 hv = *(const bf16x4*)(hbuf + (size_t)node*1024 + c);
    const float* cb = cbias + c;
    bf16x4 outv;
    outv[0] = (bf16_t)((float)hv[0] + fmaxf(a0*invd + cb[0], 0.f));
    outv[1] = (bf16_t)((float)hv[1] + fmaxf(a1*invd + cb[1], 0.f));
    outv[2] = (bf16_t)((float)hv[2] + fmaxf(a2*invd + cb[2], 0.f));
    outv[3] = (bf16_t)((float)hv[3] + fmaxf(a3*invd + cb[3], 0.f));
    *(bf16x4*)(hbuf + (size_t)node*1024 + c) = outv;
}

// ---------------------------------------------------------------- launch
extern "C" void kernel_launch(void* const* d_in, const int* in_sizes, int n_in,
                              void* d_out, int out_size, void* d_ws, size_t ws_size,
                              hipStream_t stream)
{
    (void)in_sizes; (void)n_in; (void)out_size; (void)ws_size;
    const float* x     = (const float*)d_in[0];
    const int*   eidx  = (const int*)d_in[1];
    const int*   etype = (const int*)d_in[2];
    const int*   ntyp  = (const int*)d_in[3];
    const float* nte   = (const float*)d_in[4];
    const float* ete   = (const float*)d_in[5];
    const float* Wl    = (const float*)d_in[6];
    const float* bl    = (const float*)d_in[7];
    const float* Wr    = (const float*)d_in[8];
    const float* br    = (const float*)d_in[9];
    const float* We    = (const float*)d_in[10];
    const float* attw  = (const float*)d_in[11];
    const float* cbias = (const float*)d_in[12];
    const float* outW  = (const float*)d_in[13];
    const float* outb  = (const float*)d_in[14];
    const int* srcs = eidx;
    const int* dsts = eidx + EE;

    char* wsp = (char*)d_ws;
    size_t off = 0;
    auto carve = [&](size_t bytes) -> void* {
        void* pp = wsp + off;
        off += (bytes + 255) & ~(size_t)255;
        return pp;
    };
    bf16_t* hbuf  = (bf16_t*)carve((size_t)MPAD*1024*2);
    bf16_t* XLXR  = (bf16_t*)carve((size_t)MPAD*2048*2);
    bf16_t* WT    = (bf16_t*)carve((size_t)LL*2048*1024*2);
    bf16_t* OWT   = (bf16_t*)carve((size_t)1024*1024*2);
    float*  M3L   = (float*)carve((size_t)LL*3072*4);
    float*  biasb = (float*)carve(5120*4);
    int* deg3    = (int*)carve((size_t)3*NN*4);
    int* rp3     = (int*)carve((size_t)(3*NN+1)*4);
    int* cursor3 = (int*)carve((size_t)3*NN*4);
    int* ssrc    = (int*)carve((size_t)EE*4);

    preamble<<<10338, 256, 0, stream>>>(Wl, Wr, outW, WT, OWT,
                                        x, ntyp, nte, hbuf,
                                        bl, br, outb, biasb, M3L, deg3);
    compute_m3_all<<<512, 256, 0, stream>>>(ete, We, M3L);
    hist_k<<<(EE + 255)/256, 256, 0, stream>>>(dsts, etype, deg3);
    scan_csr<<<1, 1024, 0, stream>>>(deg3, rp3, cursor3);
    fill_csr<<<(EE + 255)/256, 256, 0, stream>>>(srcs, dsts, etype, cursor3, ssrc);

    for (int l = 0; l < LL; ++l) {
        gemm_bt<bf16_t><<<79*16, 256, 0, stream>>>(hbuf, WT + (size_t)l*2048*1024,
                                                   biasb + l*2048, XLXR,
                                                   1024, 2048, MPAD, 79, 16);
        fused_edge<<<NN, 256, 0, stream>>>(rp3, ssrc, XLXR, M3L + l*3072, attw + l*1024,
                                           cbias + l*1024, hbuf);
    }

    gemm_bt<float><<<79*8, 256, 0, stream>>>(hbuf, OWT, biasb + 4096, (float*)d_out,
                                             1024, 1024, NN, 79, 8);
}

// Round 5
// 409.578 us; speedup vs baseline: 1.3726x; 1.0439x over previous
//
#include <hip/hip_runtime.h>
#include <hip/hip_bf16.h>
#include <stdint.h>

typedef __bf16 bf16_t;
typedef bf16_t bf16x8 __attribute__((ext_vector_type(8)));
typedef bf16_t bf16x4 __attribute__((ext_vector_type(4)));
typedef float f32x4 __attribute__((ext_vector_type(4)));

#define NN 10000
#define EE 80000
#define DD 1024
#define LL 2
#define MPAD 10112   /* 79*128 */
#define NEGS 0.2f

#define GLOAD_LDS16(g, l) \
    __builtin_amdgcn_global_load_lds((__attribute__((address_space(1))) void*)(void*)(g), \
                                     (__attribute__((address_space(3))) void*)(l), 16, 0, 0)

// ---------------------------------------------------------------- mega-preamble
// transpose: 64x64 tiles, f32x4 reads, pad-65 LDS (2-way only), bf16x8 writes
__global__ __launch_bounds__(256)
void preamble(const float* __restrict__ Wl, const float* __restrict__ Wr,
              const float* __restrict__ outW, bf16_t* __restrict__ WT,
              bf16_t* __restrict__ OWT,
              const float* __restrict__ x, const int* __restrict__ ntypes,
              const float* __restrict__ nte, bf16_t* __restrict__ hbuf,
              const float* __restrict__ bl, const float* __restrict__ br,
              const float* __restrict__ outb, float* __restrict__ biasb,
              float* __restrict__ M3L, int* __restrict__ deg3)
{
    __shared__ float tile[64][65];
    int b = blockIdx.x;
    int tid = threadIdx.x;
    if (b < 1280) {
        int z = b >> 8, rem = b & 255;
        int bx = rem & 15, by = rem >> 4;
        const float* src;
        bf16_t* dstp;
        switch (z) {
            case 0: src = Wl;                       dstp = WT;                        break;
            case 1: src = Wr;                       dstp = WT + (size_t)1024*1024;    break;
            case 2: src = Wl + (size_t)1024*1024;   dstp = WT + (size_t)2*1024*1024;  break;
            case 3: src = Wr + (size_t)1024*1024;   dstp = WT + (size_t)3*1024*1024;  break;
            default: src = outW;                    dstp = OWT;                       break;
        }
        int tx = tid & 15, ty = tid >> 4;      // tx: 4-col group, ty: row (16/pass)
#pragma unroll
        for (int p = 0; p < 4; ++p) {
            int r = ty + p*16;
            f32x4 rv = *(const f32x4*)(src + (size_t)(by*64 + r)*1024 + bx*64 + tx*4);
#pragma unroll
            for (int j = 0; j < 4; ++j) tile[r][tx*4 + j] = rv[j];
        }
        __syncthreads();
        int v = tid & 7, u0 = tid >> 3;        // v: 8-col group of output, u: out row
#pragma unroll
        for (int p = 0; p < 2; ++p) {
            int u = u0 + p*32;
            bf16x8 ov;
#pragma unroll
            for (int j = 0; j < 8; ++j) ov[j] = (bf16_t)tile[v*8 + j][u];
            *(bf16x8*)(dstp + (size_t)(bx*64 + u)*1024 + by*64 + v*8) = ov;
        }
    } else if (b < 6336) {
        size_t idx = ((size_t)(b - 1280)*256 + tid) * 8;
        if (idx >= (size_t)MPAD*1024) return;
        int n = (int)(idx >> 10);
        int c = (int)(idx & 1023);
        bf16x8 outv;
        if (n < NN) {
            const float* xp = x + (size_t)n*1024 + c;
            int t = ntypes[n];
            const float* ep = nte + (size_t)t*1024 + c;
#pragma unroll
            for (int j = 0; j < 8; ++j) outv[j] = (bf16_t)(xp[j] + ep[j]);
        } else {
#pragma unroll
            for (int j = 0; j < 8; ++j) outv[j] = (bf16_t)0.f;
        }
        *(bf16x8*)(hbuf + idx) = outv;
    } else if (b < 6356) {
        int i = (b - 6336)*256 + tid;
        if (i < 4096) {
            int l = i >> 11, j = i & 2047;
            biasb[i] = (j < 1024) ? bl[l*1024 + j] : br[l*1024 + j - 1024];
        } else if (i < 5120) {
            biasb[i] = outb[i - 4096];
        }
    } else if (b < 6380) {
        int i = (b - 6356)*256 + tid;
        if (i < LL*3072) M3L[i] = 0.f;
    } else {
        int i = (b - 6380)*256 + tid;
        if (i < 3*NN) deg3[i] = 0;
    }
}

// ---------------------------------------------------------------- M3 (both layers, one launch)
__global__ __launch_bounds__(256)
void compute_m3_all(const float* __restrict__ ete, const float* __restrict__ We,
                    float* __restrict__ M3L)
{
    int l   = blockIdx.x >> 8;
    int bid = blockIdx.x & 255;
    const float* WeL = We + (size_t)l*1024*1024;
    float* M3 = M3L + l*3072;
    int j  = (bid & 3) * 256 + threadIdx.x;
    int k0 = (bid >> 2) * 16;
    float a0 = 0.f, a1 = 0.f, a2 = 0.f;
#pragma unroll
    for (int kk = 0; kk < 16; ++kk) {
        int k = k0 + kk;
        float w = WeL[(size_t)k*1024 + j];
        a0 += ete[k]        * w;
        a1 += ete[1024 + k] * w;
        a2 += ete[2048 + k] * w;
    }
    atomicAdd(&M3[j],        a0);
    atomicAdd(&M3[1024 + j], a1);
    atomicAdd(&M3[2048 + j], a2);
}

// ---------------------------------------------------------------- CSR build (type-segmented)
__global__ void hist_k(const int* __restrict__ dsts, const int* __restrict__ etype,
                       int* __restrict__ deg3)
{
    int e = blockIdx.x*256 + threadIdx.x;
    if (e < EE) atomicAdd(&deg3[dsts[e]*3 + etype[e]], 1);
}

__global__ __launch_bounds__(1024)
void scan_csr(const int* __restrict__ deg3, int* __restrict__ rp3, int* __restrict__ cursor3)
{
    __shared__ int tot[1024];
    int t = threadIdx.x;
    int base = t * 30;
    int v[30];
    int run = 0;
#pragma unroll
    for (int j = 0; j < 30; ++j) {
        int i = base + j;
        int d = (i < 3*NN) ? deg3[i] : 0;
        run += d;
        v[j] = run;
    }
    tot[t] = run;
    __syncthreads();
    for (int d = 1; d < 1024; d <<= 1) {
        int xv = (t >= d) ? tot[t - d] : 0;
        __syncthreads();
        tot[t] += xv;
        __syncthreads();
    }
    int ex = (t == 0) ? 0 : tot[t - 1];
#pragma unroll
    for (int j = 0; j < 30; ++j) {
        int i = base + j;
        if (i < 3*NN) {
            int incl = ex + v[j];
            rp3[i + 1] = incl;
            if (i + 1 < 3*NN) cursor3[i + 1] = incl;
        }
    }
    if (t == 0) { rp3[0] = 0; cursor3[0] = 0; }
}

__global__ void fill_csr(const int* __restrict__ srcs, const int* __restrict__ dsts,
                         const int* __restrict__ etype, int* __restrict__ cursor3,
                         int* __restrict__ sorted_src)
{
    int e = blockIdx.x*256 + threadIdx.x;
    if (e < EE) {
        int d = dsts[e];
        int t = etype[e];
        int pos = atomicAdd(&cursor3[d*3 + t], 1);
        sorted_src[pos] = srcs[e];
    }
}

// ---------------------------------------------------------------- GEMM: BK=64 + XOR-swizzled LDS
// (proven m97-structure: 32 KiB LDS, 80 VGPR -> 5 blocks/CU, whole grid co-resident)
template <typename OT>
__global__ __launch_bounds__(256)
void gemm_bt(const bf16_t* __restrict__ A, const bf16_t* __restrict__ BT,
             const float* __restrict__ bias, OT* __restrict__ Cmat,
             int K, int Ntot, int storeM, int mtiles, int ntiles)
{
    __shared__ __align__(16) bf16_t As[128*64];
    __shared__ __align__(16) bf16_t Bs[128*64];
    const int tid  = threadIdx.x;
    const int wave = tid >> 6;
    const int lane = tid & 63;

    const int GROUP_M = 8;
    int pid = blockIdx.x;
    int in_group = GROUP_M * ntiles;
    int gid = pid / in_group;
    int first_m = gid * GROUP_M;
    int gsz = mtiles - first_m; if (gsz > GROUP_M) gsz = GROUP_M;
    int local = pid % in_group;
    const int m0 = (first_m + (local % gsz)) * 128;
    const int n0 = (local / gsz) * 128;

    const int wm = (wave & 1) * 64;
    const int wn = (wave >> 1) * 64;
    const int quad = lane >> 4;
    const int l16  = lane & 15;

    const int srow = lane >> 3;
    const int gcol = ((lane & 7) ^ srow) * 8;

    f32x4 acc[4][4];
    f32x4 zero = {0.f, 0.f, 0.f, 0.f};
#pragma unroll
    for (int i = 0; i < 4; ++i)
#pragma unroll
        for (int j = 0; j < 4; ++j) acc[i][j] = zero;

    const bf16_t* aBase = A  + (size_t)(m0 + wave*8 + srow) * K + gcol;
    const bf16_t* bBase = BT + (size_t)(n0 + wave*8 + srow) * K + gcol;
    bf16_t* asDst = As + wave*512;
    bf16_t* bsDst = Bs + wave*512;

    for (int k0 = 0; k0 < K; k0 += 64) {
#pragma unroll
        for (int j = 0; j < 4; ++j)
            GLOAD_LDS16(aBase + (size_t)(j*32)*K + k0, asDst + j*2048);
#pragma unroll
        for (int j = 0; j < 4; ++j)
            GLOAD_LDS16(bBase + (size_t)(j*32)*K + k0, bsDst + j*2048);
        __syncthreads();
#pragma unroll
        for (int kk = 0; kk < 2; ++kk) {
            bf16x8 af[4], bfr[4];
#pragma unroll
            for (int mi = 0; mi < 4; ++mi) {
                int row = wm + mi*16 + l16;
                int ch  = ((kk*4 + quad) ^ (row & 7)) * 8;
                af[mi] = *(const bf16x8*)(As + row*64 + ch);
            }
#pragma unroll
            for (int ni = 0; ni < 4; ++ni) {
                int row = wn + ni*16 + l16;
                int ch  = ((kk*4 + quad) ^ (row & 7)) * 8;
                bfr[ni] = *(const bf16x8*)(Bs + row*64 + ch);
            }
#pragma unroll
            for (int mi = 0; mi < 4; ++mi)
#pragma unroll
                for (int ni = 0; ni < 4; ++ni)
                    acc[mi][ni] = __builtin_amdgcn_mfma_f32_16x16x32_bf16(af[mi], bfr[ni], acc[mi][ni], 0, 0, 0);
        }
        __syncthreads();
    }

#pragma unroll
    for (int mi = 0; mi < 4; ++mi) {
#pragma unroll
        for (int ni = 0; ni < 4; ++ni) {
            int col = n0 + wn + ni*16 + l16;
            float bv = bias[col];
#pragma unroll
            for (int r = 0; r < 4; ++r) {
                int row = m0 + wm + mi*16 + quad*4 + r;
                if (row < storeM)
                    Cmat[(size_t)row * Ntot + col] = (OT)(acc[mi][ni][r] + bv);
            }
        }
    }
}

// ---------------------------------------------------------------- fused: logits + softmax + aggregate + residual
// v4: type-segmented CSR (static per-type regs) + 8 ch/lane, 128 threads/node.
// Per edge: 2 VMEM (16B/lane), 4-shfl head reduce (16 lanes = 128ch = 1 head), 2 exp.
__global__ __launch_bounds__(128)
void fused_edge(const int* __restrict__ rp3, const int* __restrict__ ssrc,
                const bf16_t* __restrict__ XLXR,
                const float* __restrict__ M3, const float* __restrict__ attv,
                const float* __restrict__ cbias, bf16_t* __restrict__ hbuf)
{
    int node = blockIdx.x;
    int q = threadIdx.x;     // 0..127
    int c8 = q * 8;
    __shared__ int s_src[128];

    int b   = rp3[3*node];
    int t1g = rp3[3*node + 1];
    int t2g = rp3[3*node + 2];
    int en  = rp3[3*node + 3];

    bf16x8 xlv = *(const bf16x8*)(XLXR + (size_t)node*2048 + c8);
    bf16x8 xrv = *(const bf16x8*)(XLXR + (size_t)node*2048 + 1024 + c8);
    float xr[8], at[8], q0[8], q1[8], q2[8];
#pragma unroll
    for (int j = 0; j < 8; ++j) xr[j] = (float)xrv[j];
    f32x4 a_lo = *(const f32x4*)(attv + c8);
    f32x4 a_hi = *(const f32x4*)(attv + c8 + 4);
#pragma unroll
    for (int j = 0; j < 4; ++j) { at[j] = a_lo[j]; at[4+j] = a_hi[j]; }
#pragma unroll
    for (int j = 0; j < 8; ++j) {
        q0[j] = xr[j] + M3[c8 + j];
        q1[j] = xr[j] + M3[1024 + c8 + j];
        q2[j] = xr[j] + M3[2048 + c8 + j];
    }

    float acc[8] = {0.f, 0.f, 0.f, 0.f, 0.f, 0.f, 0.f, 0.f};
    float den = 0.f;

    auto body = [&](int li, const float (&p)[8]) {
        int s = s_src[li];
        bf16x8 xs = *(const bf16x8*)(XLXR + (size_t)s*2048 + c8);
        float x[8];
        float part = 0.f;
#pragma unroll
        for (int j = 0; j < 8; ++j) {
            x[j] = (float)xs[j];
            float v = x[j] + p[j];
            v = fmaxf(v, NEGS * v);       // leaky_relu
            part += v * at[j];
        }
        part += __shfl_xor(part, 1);
        part += __shfl_xor(part, 2);
        part += __shfl_xor(part, 4);
        part += __shfl_xor(part, 8);
        part = fminf(fmaxf(part, -60.f), 60.f);
        float pe = __expf(part);
        den += pe;
#pragma unroll
        for (int j = 0; j < 8; ++j) acc[j] += pe * x[j];
    };

    for (int base = b; base < en; base += 128) {
        int hi = en - base; if (hi > 128) hi = 128;
        hi += base;                       // global end of this chunk
        __syncthreads();
        if (q < hi - base) s_src[q] = ssrc[base + q];
        __syncthreads();
        int e0 = (t1g < hi) ? t1g : hi;
        int e1 = (t2g < hi) ? t2g : hi;
        int s1 = (t1g > base) ? t1g : base;
        int s2 = (t2g > base) ? t2g : base;
#pragma unroll 2
        for (int i = base; i < e0; ++i) body(i - base, q0);
#pragma unroll 2
        for (int i = s1; i < e1; ++i)   body(i - base, q1);
#pragma unroll 2
        for (int i = s2; i < hi; ++i)   body(i - base, q2);
    }

    float cnt0 = (float)(t1g - b);
    float cnt1 = (float)(t2g - t1g);
    float cnt2 = (float)(en - t2g);
    float degf = cnt0 + cnt1 + cnt2;
    float inv = 1.f / fmaxf(degf, 1.f);
    float w0 = cnt0 * inv, w1 = cnt1 * inv, w2 = cnt2 * inv;
    float sw = w0 + w1 + w2;              // 1 if deg>0 else 0
    float sx[8];
    float sp = 0.f;
#pragma unroll
    for (int j = 0; j < 8; ++j) {
        sx[j] = (float)xlv[j];
        float u = sx[j] + xr[j]*(1.f - sw) + w0*q0[j] + w1*q1[j] + w2*q2[j];
        u = fmaxf(u, NEGS * u);
        sp += u * at[j];
    }
    sp += __shfl_xor(sp, 1);
    sp += __shfl_xor(sp, 2);
    sp += __shfl_xor(sp, 4);
    sp += __shfl_xor(sp, 8);
    sp = fminf(fmaxf(sp, -60.f), 60.f);
    float ps = __expf(sp);
    den += ps;
#pragma unroll
    for (int j = 0; j < 8; ++j) acc[j] += ps * sx[j];

    float invd = 1.f / den;
    bf16x8 hv = *(const bf16x8*)(hbuf + (size_t)node*1024 + c8);
    bf16x8 outv;
#pragma unroll
    for (int j = 0; j < 8; ++j)
        outv[j] = (bf16_t)((float)hv[j] + fmaxf(acc[j]*invd + cbias[c8 + j], 0.f));
    *(bf16x8*)(hbuf + (size_t)node*1024 + c8) = outv;
}

// ---------------------------------------------------------------- launch
extern "C" void kernel_launch(void* const* d_in, const int* in_sizes, int n_in,
                              void* d_out, int out_size, void* d_ws, size_t ws_size,
                              hipStream_t stream)
{
    (void)in_sizes; (void)n_in; (void)out_size; (void)ws_size;
    const float* x     = (const float*)d_in[0];
    const int*   eidx  = (const int*)d_in[1];
    const int*   etype = (const int*)d_in[2];
    const int*   ntyp  = (const int*)d_in[3];
    const float* nte   = (const float*)d_in[4];
    const float* ete   = (const float*)d_in[5];
    const float* Wl    = (const float*)d_in[6];
    const float* bl    = (const float*)d_in[7];
    const float* Wr    = (const float*)d_in[8];
    const float* br    = (const float*)d_in[9];
    const float* We    = (const float*)d_in[10];
    const float* attw  = (const float*)d_in[11];
    const float* cbias = (const float*)d_in[12];
    const float* outW  = (const float*)d_in[13];
    const float* outb  = (const float*)d_in[14];
    const int* srcs = eidx;
    const int* dsts = eidx + EE;

    char* wsp = (char*)d_ws;
    size_t off = 0;
    auto carve = [&](size_t bytes) -> void* {
        void* pp = wsp + off;
        off += (bytes + 255) & ~(size_t)255;
        return pp;
    };
    bf16_t* hbuf  = (bf16_t*)carve((size_t)MPAD*1024*2);
    bf16_t* XLXR  = (bf16_t*)carve((size_t)MPAD*2048*2);
    bf16_t* WT    = (bf16_t*)carve((size_t)LL*2048*1024*2);
    bf16_t* OWT   = (bf16_t*)carve((size_t)1024*1024*2);
    float*  M3L   = (float*)carve((size_t)LL*3072*4);
    float*  biasb = (float*)carve(5120*4);
    int* deg3    = (int*)carve((size_t)3*NN*4);
    int* rp3     = (int*)carve((size_t)(3*NN+1)*4);
    int* cursor3 = (int*)carve((size_t)3*NN*4);
    int* ssrc    = (int*)carve((size_t)EE*4);

    preamble<<<6498, 256, 0, stream>>>(Wl, Wr, outW, WT, OWT,
                                       x, ntyp, nte, hbuf,
                                       bl, br, outb, biasb, M3L, deg3);
    compute_m3_all<<<512, 256, 0, stream>>>(ete, We, M3L);
    hist_k<<<(EE + 255)/256, 256, 0, stream>>>(dsts, etype, deg3);
    scan_csr<<<1, 1024, 0, stream>>>(deg3, rp3, cursor3);
    fill_csr<<<(EE + 255)/256, 256, 0, stream>>>(srcs, dsts, etype, cursor3, ssrc);

    for (int l = 0; l < LL; ++l) {
        gemm_bt<bf16_t><<<79*16, 256, 0, stream>>>(hbuf, WT + (size_t)l*2048*1024,
                                                   biasb + l*2048, XLXR,
                                                   1024, 2048, MPAD, 79, 16);
        fused_edge<<<NN, 128, 0, stream>>>(rp3, ssrc, XLXR, M3L + l*3072, attw + l*1024,
                                           cbias + l*1024, hbuf);
    }

    gemm_bt<float><<<79*8, 256, 0, stream>>>(hbuf, OWT, biasb + 4096, (float*)d_out,
                                             1024, 1024, NN, 79, 8);
}

// Round 6
// 406.907 us; speedup vs baseline: 1.3816x; 1.0066x over previous
//
#include <hip/hip_runtime.h>
#include <hip/hip_bf16.h>
#include <stdint.h>

typedef __bf16 bf16_t;
typedef bf16_t bf16x8 __attribute__((ext_vector_type(8)));
typedef bf16_t bf16x4 __attribute__((ext_vector_type(4)));
typedef float f32x4 __attribute__((ext_vector_type(4)));

#define NN 10000
#define EE 80000
#define DD 1024
#define LL 2
#define MPAD 10112   /* 79*128 */
#define NEGS 0.2f

#define GLOAD_LDS16(g, l) \
    __builtin_amdgcn_global_load_lds((__attribute__((address_space(1))) void*)(void*)(g), \
                                     (__attribute__((address_space(3))) void*)(l), 16, 0, 0)

// ---------------------------------------------------------------- mega-preamble
// transpose: 64x64 tiles, f32x4 reads, pad-65 LDS (2-way only), bf16x8 writes
__global__ __launch_bounds__(256)
void preamble(const float* __restrict__ Wl, const float* __restrict__ Wr,
              const float* __restrict__ outW, bf16_t* __restrict__ WT,
              bf16_t* __restrict__ OWT,
              const float* __restrict__ x, const int* __restrict__ ntypes,
              const float* __restrict__ nte, bf16_t* __restrict__ hbuf,
              const float* __restrict__ bl, const float* __restrict__ br,
              const float* __restrict__ outb, float* __restrict__ biasb,
              float* __restrict__ M3L, int* __restrict__ deg3)
{
    __shared__ float tile[64][65];
    int b = blockIdx.x;
    int tid = threadIdx.x;
    if (b < 1280) {
        int z = b >> 8, rem = b & 255;
        int bx = rem & 15, by = rem >> 4;
        const float* src;
        bf16_t* dstp;
        switch (z) {
            case 0: src = Wl;                       dstp = WT;                        break;
            case 1: src = Wr;                       dstp = WT + (size_t)1024*1024;    break;
            case 2: src = Wl + (size_t)1024*1024;   dstp = WT + (size_t)2*1024*1024;  break;
            case 3: src = Wr + (size_t)1024*1024;   dstp = WT + (size_t)3*1024*1024;  break;
            default: src = outW;                    dstp = OWT;                       break;
        }
        int tx = tid & 15, ty = tid >> 4;      // tx: 4-col group, ty: row (16/pass)
#pragma unroll
        for (int p = 0; p < 4; ++p) {
            int r = ty + p*16;
            f32x4 rv = *(const f32x4*)(src + (size_t)(by*64 + r)*1024 + bx*64 + tx*4);
#pragma unroll
            for (int j = 0; j < 4; ++j) tile[r][tx*4 + j] = rv[j];
        }
        __syncthreads();
        int v = tid & 7, u0 = tid >> 3;        // v: 8-col group of output, u: out row
#pragma unroll
        for (int p = 0; p < 2; ++p) {
            int u = u0 + p*32;
            bf16x8 ov;
#pragma unroll
            for (int j = 0; j < 8; ++j) ov[j] = (bf16_t)tile[v*8 + j][u];
            *(bf16x8*)(dstp + (size_t)(bx*64 + u)*1024 + by*64 + v*8) = ov;
        }
    } else if (b < 6336) {
        size_t idx = ((size_t)(b - 1280)*256 + tid) * 8;
        if (idx >= (size_t)MPAD*1024) return;
        int n = (int)(idx >> 10);
        int c = (int)(idx & 1023);
        bf16x8 outv;
        if (n < NN) {
            const float* xp = x + (size_t)n*1024 + c;
            int t = ntypes[n];
            const float* ep = nte + (size_t)t*1024 + c;
            f32x4 xa = *(const f32x4*)(xp);
            f32x4 xb = *(const f32x4*)(xp + 4);
            f32x4 ea = *(const f32x4*)(ep);
            f32x4 eb = *(const f32x4*)(ep + 4);
#pragma unroll
            for (int j = 0; j < 4; ++j) {
                outv[j]     = (bf16_t)(xa[j] + ea[j]);
                outv[4 + j] = (bf16_t)(xb[j] + eb[j]);
            }
        } else {
#pragma unroll
            for (int j = 0; j < 8; ++j) outv[j] = (bf16_t)0.f;
        }
        *(bf16x8*)(hbuf + idx) = outv;
    } else if (b < 6356) {
        int i = (b - 6336)*256 + tid;
        if (i < 4096) {
            int l = i >> 11, j = i & 2047;
            biasb[i] = (j < 1024) ? bl[l*1024 + j] : br[l*1024 + j - 1024];
        } else if (i < 5120) {
            biasb[i] = outb[i - 4096];
        }
    } else if (b < 6380) {
        int i = (b - 6356)*256 + tid;
        if (i < LL*3072) M3L[i] = 0.f;
    } else {
        int i = (b - 6380)*256 + tid;
        if (i < 3*NN) deg3[i] = 0;
    }
}

// ---------------------------------------------------------------- M3 (both layers, one launch)
__global__ __launch_bounds__(256)
void compute_m3_all(const float* __restrict__ ete, const float* __restrict__ We,
                    float* __restrict__ M3L)
{
    int l   = blockIdx.x >> 8;
    int bid = blockIdx.x & 255;
    const float* WeL = We + (size_t)l*1024*1024;
    float* M3 = M3L + l*3072;
    int j  = (bid & 3) * 256 + threadIdx.x;
    int k0 = (bid >> 2) * 16;
    float a0 = 0.f, a1 = 0.f, a2 = 0.f;
#pragma unroll
    for (int kk = 0; kk < 16; ++kk) {
        int k = k0 + kk;
        float w = WeL[(size_t)k*1024 + j];
        a0 += ete[k]        * w;
        a1 += ete[1024 + k] * w;
        a2 += ete[2048 + k] * w;
    }
    atomicAdd(&M3[j],        a0);
    atomicAdd(&M3[1024 + j], a1);
    atomicAdd(&M3[2048 + j], a2);
}

// ---------------------------------------------------------------- CSR build (type-segmented)
__global__ void hist_k(const int* __restrict__ dsts, const int* __restrict__ etype,
                       int* __restrict__ deg3)
{
    int e = blockIdx.x*256 + threadIdx.x;
    if (e < EE) atomicAdd(&deg3[dsts[e]*3 + etype[e]], 1);
}

__global__ __launch_bounds__(1024)
void scan_csr(const int* __restrict__ deg3, int* __restrict__ rp3, int* __restrict__ cursor3)
{
    __shared__ int tot[1024];
    int t = threadIdx.x;
    int base = t * 30;
    int v[30];
    int run = 0;
#pragma unroll
    for (int j = 0; j < 30; ++j) {
        int i = base + j;
        int d = (i < 3*NN) ? deg3[i] : 0;
        run += d;
        v[j] = run;
    }
    tot[t] = run;
    __syncthreads();
    for (int d = 1; d < 1024; d <<= 1) {
        int xv = (t >= d) ? tot[t - d] : 0;
        __syncthreads();
        tot[t] += xv;
        __syncthreads();
    }
    int ex = (t == 0) ? 0 : tot[t - 1];
#pragma unroll
    for (int j = 0; j < 30; ++j) {
        int i = base + j;
        if (i < 3*NN) {
            int incl = ex + v[j];
            rp3[i + 1] = incl;
            if (i + 1 < 3*NN) cursor3[i + 1] = incl;
        }
    }
    if (t == 0) { rp3[0] = 0; cursor3[0] = 0; }
}

__global__ void fill_csr(const int* __restrict__ srcs, const int* __restrict__ dsts,
                         const int* __restrict__ etype, int* __restrict__ cursor3,
                         int* __restrict__ sorted_src)
{
    int e = blockIdx.x*256 + threadIdx.x;
    if (e < EE) {
        int d = dsts[e];
        int t = etype[e];
        int pos = atomicAdd(&cursor3[d*3 + t], 1);
        sorted_src[pos] = srcs[e];
    }
}

// ---------------------------------------------------------------- GEMM: BK=64 + XOR-swizzled LDS
// (proven m97-structure: 32 KiB LDS, 80 VGPR -> 5 blocks/CU, whole grid co-resident)
template <typename OT>
__global__ __launch_bounds__(256)
void gemm_bt(const bf16_t* __restrict__ A, const bf16_t* __restrict__ BT,
             const float* __restrict__ bias, OT* __restrict__ Cmat,
             int K, int Ntot, int storeM, int mtiles, int ntiles)
{
    __shared__ __align__(16) bf16_t As[128*64];
    __shared__ __align__(16) bf16_t Bs[128*64];
    const int tid  = threadIdx.x;
    const int wave = tid >> 6;
    const int lane = tid & 63;

    const int GROUP_M = 8;
    int pid = blockIdx.x;
    int in_group = GROUP_M * ntiles;
    int gid = pid / in_group;
    int first_m = gid * GROUP_M;
    int gsz = mtiles - first_m; if (gsz > GROUP_M) gsz = GROUP_M;
    int local = pid % in_group;
    const int m0 = (first_m + (local % gsz)) * 128;
    const int n0 = (local / gsz) * 128;

    const int wm = (wave & 1) * 64;
    const int wn = (wave >> 1) * 64;
    const int quad = lane >> 4;
    const int l16  = lane & 15;

    const int srow = lane >> 3;
    const int gcol = ((lane & 7) ^ srow) * 8;

    f32x4 acc[4][4];
    f32x4 zero = {0.f, 0.f, 0.f, 0.f};
#pragma unroll
    for (int i = 0; i < 4; ++i)
#pragma unroll
        for (int j = 0; j < 4; ++j) acc[i][j] = zero;

    const bf16_t* aBase = A  + (size_t)(m0 + wave*8 + srow) * K + gcol;
    const bf16_t* bBase = BT + (size_t)(n0 + wave*8 + srow) * K + gcol;
    bf16_t* asDst = As + wave*512;
    bf16_t* bsDst = Bs + wave*512;

    for (int k0 = 0; k0 < K; k0 += 64) {
#pragma unroll
        for (int j = 0; j < 4; ++j)
            GLOAD_LDS16(aBase + (size_t)(j*32)*K + k0, asDst + j*2048);
#pragma unroll
        for (int j = 0; j < 4; ++j)
            GLOAD_LDS16(bBase + (size_t)(j*32)*K + k0, bsDst + j*2048);
        __syncthreads();
#pragma unroll
        for (int kk = 0; kk < 2; ++kk) {
            bf16x8 af[4], bfr[4];
#pragma unroll
            for (int mi = 0; mi < 4; ++mi) {
                int row = wm + mi*16 + l16;
                int ch  = ((kk*4 + quad) ^ (row & 7)) * 8;
                af[mi] = *(const bf16x8*)(As + row*64 + ch);
            }
#pragma unroll
            for (int ni = 0; ni < 4; ++ni) {
                int row = wn + ni*16 + l16;
                int ch  = ((kk*4 + quad) ^ (row & 7)) * 8;
                bfr[ni] = *(const bf16x8*)(Bs + row*64 + ch);
            }
#pragma unroll
            for (int mi = 0; mi < 4; ++mi)
#pragma unroll
                for (int ni = 0; ni < 4; ++ni)
                    acc[mi][ni] = __builtin_amdgcn_mfma_f32_16x16x32_bf16(af[mi], bfr[ni], acc[mi][ni], 0, 0, 0);
        }
        __syncthreads();
    }

#pragma unroll
    for (int mi = 0; mi < 4; ++mi) {
#pragma unroll
        for (int ni = 0; ni < 4; ++ni) {
            int col = n0 + wn + ni*16 + l16;
            float bv = bias[col];
#pragma unroll
            for (int r = 0; r < 4; ++r) {
                int row = m0 + wm + mi*16 + quad*4 + r;
                if (row < storeM)
                    Cmat[(size_t)row * Ntot + col] = (OT)(acc[mi][ni][r] + bv);
            }
        }
    }
}

// ---------------------------------------------------------------- fused: logits + softmax + aggregate + residual
// v5: type-segmented CSR, 8 ch/lane, 128 threads/node, 2 nodes/block.
// NO LDS, NO syncthreads: edge indices are wave-uniform -> scalar-path loads.
__global__ __launch_bounds__(256)
void fused_edge(const int* __restrict__ rp3, const int* __restrict__ ssrc,
                const bf16_t* __restrict__ XLXR,
                const float* __restrict__ M3, const float* __restrict__ attv,
                const float* __restrict__ cbias, bf16_t* __restrict__ hbuf)
{
    int node = blockIdx.x*2 + (threadIdx.x >> 7);
    int q = threadIdx.x & 127;   // 0..127, 8 ch each
    int c8 = q * 8;

    // force wave-uniform (SGPR) CSR bounds -> scalar loop + s_load of ssrc
    int b   = __builtin_amdgcn_readfirstlane(rp3[3*node]);
    int t1g = __builtin_amdgcn_readfirstlane(rp3[3*node + 1]);
    int t2g = __builtin_amdgcn_readfirstlane(rp3[3*node + 2]);
    int en  = __builtin_amdgcn_readfirstlane(rp3[3*node + 3]);

    bf16x8 xlv = *(const bf16x8*)(XLXR + (size_t)node*2048 + c8);
    bf16x8 xrv = *(const bf16x8*)(XLXR + (size_t)node*2048 + 1024 + c8);
    float xr[8], at[8], q0[8], q1[8], q2[8];
#pragma unroll
    for (int j = 0; j < 8; ++j) xr[j] = (float)xrv[j];
    f32x4 a_lo = *(const f32x4*)(attv + c8);
    f32x4 a_hi = *(const f32x4*)(attv + c8 + 4);
#pragma unroll
    for (int j = 0; j < 4; ++j) { at[j] = a_lo[j]; at[4+j] = a_hi[j]; }
#pragma unroll
    for (int j = 0; j < 8; ++j) {
        q0[j] = xr[j] + M3[c8 + j];
        q1[j] = xr[j] + M3[1024 + c8 + j];
        q2[j] = xr[j] + M3[2048 + c8 + j];
    }

    float acc[8] = {0.f, 0.f, 0.f, 0.f, 0.f, 0.f, 0.f, 0.f};
    float den = 0.f;

    auto body = [&](int i, const float (&p)[8]) {
        int s = ssrc[i];             // wave-uniform address
        bf16x8 xs = *(const bf16x8*)(XLXR + (size_t)s*2048 + c8);
        float x[8];
        float part = 0.f;
#pragma unroll
        for (int j = 0; j < 8; ++j) {
            x[j] = (float)xs[j];
            float v = x[j] + p[j];
            v = fmaxf(v, NEGS * v);       // leaky_relu
            part += v * at[j];
        }
        part += __shfl_xor(part, 1);
        part += __shfl_xor(part, 2);
        part += __shfl_xor(part, 4);
        part += __shfl_xor(part, 8);
        part = fminf(fmaxf(part, -60.f), 60.f);
        float pe = __expf(part);
        den += pe;
#pragma unroll
        for (int j = 0; j < 8; ++j) acc[j] += pe * x[j];
    };

#pragma unroll 2
    for (int i = b; i < t1g; ++i)   body(i, q0);
#pragma unroll 2
    for (int i = t1g; i < t2g; ++i) body(i, q1);
#pragma unroll 2
    for (int i = t2g; i < en; ++i)  body(i, q2);

    float cnt0 = (float)(t1g - b);
    float cnt1 = (float)(t2g - t1g);
    float cnt2 = (float)(en - t2g);
    float degf = cnt0 + cnt1 + cnt2;
    float inv = 1.f / fmaxf(degf, 1.f);
    float w0 = cnt0 * inv, w1 = cnt1 * inv, w2 = cnt2 * inv;
    float sw = w0 + w1 + w2;              // 1 if deg>0 else 0
    float sx[8];
    float sp = 0.f;
#pragma unroll
    for (int j = 0; j < 8; ++j) {
        sx[j] = (float)xlv[j];
        float u = sx[j] + xr[j]*(1.f - sw) + w0*q0[j] + w1*q1[j] + w2*q2[j];
        u = fmaxf(u, NEGS * u);
        sp += u * at[j];
    }
    sp += __shfl_xor(sp, 1);
    sp += __shfl_xor(sp, 2);
    sp += __shfl_xor(sp, 4);
    sp += __shfl_xor(sp, 8);
    sp = fminf(fmaxf(sp, -60.f), 60.f);
    float ps = __expf(sp);
    den += ps;
#pragma unroll
    for (int j = 0; j < 8; ++j) acc[j] += ps * sx[j];

    float invd = 1.f / den;
    bf16x8 hv = *(const bf16x8*)(hbuf + (size_t)node*1024 + c8);
    bf16x8 outv;
#pragma unroll
    for (int j = 0; j < 8; ++j)
        outv[j] = (bf16_t)((float)hv[j] + fmaxf(acc[j]*invd + cbias[c8 + j], 0.f));
    *(bf16x8*)(hbuf + (size_t)node*1024 + c8) = outv;
}

// ---------------------------------------------------------------- launch
extern "C" void kernel_launch(void* const* d_in, const int* in_sizes, int n_in,
                              void* d_out, int out_size, void* d_ws, size_t ws_size,
                              hipStream_t stream)
{
    (void)in_sizes; (void)n_in; (void)out_size; (void)ws_size;
    const float* x     = (const float*)d_in[0];
    const int*   eidx  = (const int*)d_in[1];
    const int*   etype = (const int*)d_in[2];
    const int*   ntyp  = (const int*)d_in[3];
    const float* nte   = (const float*)d_in[4];
    const float* ete   = (const float*)d_in[5];
    const float* Wl    = (const float*)d_in[6];
    const float* bl    = (const float*)d_in[7];
    const float* Wr    = (const float*)d_in[8];
    const float* br    = (const float*)d_in[9];
    const float* We    = (const float*)d_in[10];
    const float* attw  = (const float*)d_in[11];
    const float* cbias = (const float*)d_in[12];
    const float* outW  = (const float*)d_in[13];
    const float* outb  = (const float*)d_in[14];
    const int* srcs = eidx;
    const int* dsts = eidx + EE;

    char* wsp = (char*)d_ws;
    size_t off = 0;
    auto carve = [&](size_t bytes) -> void* {
        void* pp = wsp + off;
        off += (bytes + 255) & ~(size_t)255;
        return pp;
    };
    bf16_t* hbuf  = (bf16_t*)carve((size_t)MPAD*1024*2);
    bf16_t* XLXR  = (bf16_t*)carve((size_t)MPAD*2048*2);
    bf16_t* WT    = (bf16_t*)carve((size_t)LL*2048*1024*2);
    bf16_t* OWT   = (bf16_t*)carve((size_t)1024*1024*2);
    float*  M3L   = (float*)carve((size_t)LL*3072*4);
    float*  biasb = (float*)carve(5120*4);
    int* deg3    = (int*)carve((size_t)3*NN*4);
    int* rp3     = (int*)carve((size_t)(3*NN+1)*4);
    int* cursor3 = (int*)carve((size_t)3*NN*4);
    int* ssrc    = (int*)carve((size_t)EE*4);

    preamble<<<6498, 256, 0, stream>>>(Wl, Wr, outW, WT, OWT,
                                       x, ntyp, nte, hbuf,
                                       bl, br, outb, biasb, M3L, deg3);
    compute_m3_all<<<512, 256, 0, stream>>>(ete, We, M3L);
    hist_k<<<(EE + 255)/256, 256, 0, stream>>>(dsts, etype, deg3);
    scan_csr<<<1, 1024, 0, stream>>>(deg3, rp3, cursor3);
    fill_csr<<<(EE + 255)/256, 256, 0, stream>>>(srcs, dsts, etype, cursor3, ssrc);

    for (int l = 0; l < LL; ++l) {
        gemm_bt<bf16_t><<<79*16, 256, 0, stream>>>(hbuf, WT + (size_t)l*2048*1024,
                                                   biasb + l*2048, XLXR,
                                                   1024, 2048, MPAD, 79, 16);
        fused_edge<<<NN/2, 256, 0, stream>>>(rp3, ssrc, XLXR, M3L + l*3072, attw + l*1024,
                                             cbias + l*1024, hbuf);
    }

    gemm_bt<float><<<79*8, 256, 0, stream>>>(hbuf, OWT, biasb + 4096, (float*)d_out,
                                             1024, 1024, NN, 79, 8);
}